// Round 1
// baseline (301.758 us; speedup 1.0000x reference)
//
#include <hip/hip_runtime.h>

#define KS   21
#define HH   48
#define WW   48
#define CC   3
#define NB   4
#define NPIX (HH*WW*CC)     /* 6912 */
#define NTOT (NB*NPIX)      /* 27648 */
#define TPB  576            /* 9 waves; 3c x 48 x 4 groups */
#define PXT  12             /* pixels per thread per conv pass */
#define SPAN (PXT + KS - 1) /* 32: 12 outputs + 20 halo */
#define PST  49             /* padded plane row stride (banks: 49 mod 32 = 17, odd) */
#define PLANE (HH*PST)      /* 2352 */
#define CTAN 2.8853900817779268f   /* 2*log2(e) */
/* x in [0,1): tanh(x-b) == -1 (+/-6.7e-4) for all x if b >= 5; == +1 if b <= -4 */
#define B_HI 5.0f
#define B_LO -4.0f

__device__ __forceinline__ float fast_exp2(float x) {
#if __has_builtin(__builtin_amdgcn_exp2f)
    return __builtin_amdgcn_exp2f(x);
#else
    return __expf(x * 0.6931471805599453f);
#endif
}
__device__ __forceinline__ float fast_rcp(float x) {
#if __has_builtin(__builtin_amdgcn_rcpf)
    return __builtin_amdgcn_rcpf(x);
#else
    return 1.0f / x;
#endif
}

// 1D L2-normalized Gaussian tap (f,i). Outer product == reference's 2D
// L2-normalized kernel (amp cancels; 2D sum-sq factorizes into (1D sum-sq)^2).
__device__ __forceinline__ float tap1d(const float* g, int f, int i) {
    float sigma  = 1.0f / g[f];
    float inv2s2 = 0.5f / (sigma * sigma);
    const float step = 21.0f / 640.0f, mean = 21.0f / 64.0f;
    float r = (float)i * step - mean;
    float v = expf(-r * r * inv2s2);
    float ss = 0.0f;
    for (int j = 0; j < KS; ++j) {
        float rj = (float)j * step - mean;
        float vj = expf(-rj * rj * inv2s2);
        ss += vj * vj;
    }
    return v * rsqrtf(ss);
}

// Horizontal conv pass, planar LDS -> planar LDS, zero padding via zeroed
// OOB window slots. Thread t: c = t/192, h = (t%192)/4, w0 = (t%4)*12.
// Sliding 32-float register window: 32 LDS reads for 12 outputs (vs 21/output).
__device__ __forceinline__ void hconv(const float* src, float* dst,
                                      const float* taps, int t) {
    const int c = t / 192, rem = t % 192, h = rem >> 2, w0 = (rem & 3) * PXT;
    const float* row = src + c * PLANE + h * PST;
    float v[SPAN];
#pragma unroll
    for (int s = 0; s < SPAN; ++s) {
        int w = w0 - 10 + s;
        v[s] = ((unsigned)w < (unsigned)WW) ? row[w] : 0.0f;
    }
    float tp[KS];
#pragma unroll
    for (int k = 0; k < KS; ++k) tp[k] = taps[c * 21 + k];
    float* drow = dst + c * PLANE + h * PST + w0;
#pragma unroll
    for (int j = 0; j < PXT; ++j) {
        float a = 0.0f;
#pragma unroll
        for (int k = 0; k < KS; ++k) a = fmaf(v[j + k], tp[k], a);
        drow[j] = a;
    }
}

// Vertical conv pass, planar LDS -> 12 registers.
// Thread t: c = t/192, hq = (t%192)/48, w = t%48; lanes 0..47 -> consecutive w
// (conflict-free ds_read), zero padding via zeroed OOB slots.
__device__ __forceinline__ void vconv(const float* src, const float* taps,
                                      int t, float* acc) {
    const int c = t / 192, rem = t % 192, h0 = (rem / 48) * PXT, w = rem % 48;
    const float* col = src + c * PLANE + w;
    float v[SPAN];
#pragma unroll
    for (int s = 0; s < SPAN; ++s) {
        int h = h0 - 10 + s;
        v[s] = ((unsigned)h < (unsigned)HH) ? col[h * PST] : 0.0f;
    }
    float tp[KS];
#pragma unroll
    for (int k = 0; k < KS; ++k) tp[k] = taps[c * 21 + k];
#pragma unroll
    for (int j = 0; j < PXT; ++j) {
        float a = 0.0f;
#pragma unroll
        for (int k = 0; k < KS; ++k) a = fmaf(v[j + k], tp[k], a);
        acc[j] = a;
    }
}

// Single fused kernel: one block per image. All intermediates in LDS/registers.
// Phases: load(planar) -> hconv_m -> vconv_m(first in regs) -> hconv_g ->
// vconv_g -> classify/compact -> pairwise tanh (usually len==0) -> hconv_w ->
// vconv_w -> out = first - second -> coalesced store.
__global__ __launch_bounds__(TPB) void inrf_fused(
    const float* __restrict__ in, const float* __restrict__ gm,
    const float* __restrict__ gw, const float* __restrict__ gg,
    float* __restrict__ out)
{
    __shared__ float bufI[CC * PLANE];   // input planar; later: difference
    __shared__ float bufB[CC * PLANE];   // hconv scratch; transiently: active list
    __shared__ float sm[63], sg[63], sw[63];
    __shared__ int s_len, s_net;

    const int t = threadIdx.x;
    const int n = blockIdx.x;
    const int lane = t & 63;

    // taps: 189 threads compute one 1D tap each
    if (t < 189) {
        int set = t / 63, f = (t % 63) / 21, i = t % 21;
        const float* g = (set == 0) ? gm : (set == 1) ? gg : gw;
        float v = tap1d(g, f, i);
        ((set == 0) ? sm : (set == 1) ? sg : sw)[t % 63] = v;
    }
    if (t == 0) { s_len = 0; s_net = 0; }

    // load NHWC -> planar [c][h][w] (row stride 49)
    const float* imgp = in + n * NPIX;
#pragma unroll
    for (int k = 0; k < PXT; ++k) {
        int j = k * TPB + t;
        int c = j % 3, hw = j / 3, w = hw % WW, h = hw / WW;
        bufI[c * PLANE + h * PST + w] = imgp[j];
    }
    __syncthreads();

    // M path: first term (stays in registers until the end)
    hconv(bufI, bufB, sm, t);
    __syncthreads();
    float first[PXT];
    vconv(bufB, sm, t, first);
    __syncthreads();

    // G path: blurred
    hconv(bufI, bufB, sg, t);
    __syncthreads();
    float bb[PXT];
    vconv(bufB, sg, t, bb);
    __syncthreads();                     // all reads of bufB done -> reuse for actives

    // classify + compact (active list into bufB; net count via ballots)
    int wnet = 0;
#pragma unroll
    for (int j = 0; j < PXT; ++j) {
        bool sp = (bb[j] <= B_LO);       // tanh == +1 for all x
        bool sn = (bb[j] >= B_HI);       // tanh == -1 for all x
        unsigned long long bp = __ballot(sp), bn = __ballot(sn);
        if (lane == 0) wnet += __popcll(bp) - __popcll(bn);
        if (!(sp | sn)) {
            int pos = atomicAdd(&s_len, 1);
            bufB[pos] = CTAN * bb[j];
        }
    }
    if (lane == 0) atomicAdd(&s_net, wnet);
    __syncthreads();

    const int len = s_len;
    const float netf = (float)s_net;

    // pairwise phase: d[p] = (net + len - 2*sum_q 1/(exp2(cx-cb_q)+1)) / NPIX
    // x read and d written in place (each pixel owned by exactly one thread)
    {
        const int c = t / 192, rem = t % 192, h0 = (rem / 48) * PXT, w = rem % 48;
        float* col = bufI + c * PLANE + w;
#pragma unroll
        for (int j = 0; j < PXT; ++j) {
            float cx = CTAN * col[(h0 + j) * PST];
            float acc = 0.0f;
            for (int q = 0; q < len; ++q)
                acc += fast_rcp(fast_exp2(cx - bufB[q]) + 1.0f);
            col[(h0 + j) * PST] = (netf + (float)len - 2.0f * acc) * (1.0f / (float)NPIX);
        }
    }
    __syncthreads();                     // d complete; active list dead

    // W path on difference
    hconv(bufI, bufB, sw, t);
    __syncthreads();
    float second[PXT];
    vconv(bufB, sw, t, second);
    __syncthreads();                     // all reads of bufI (hconv_w) long done; safe to reuse

    // out = first - second, staged planar then stored coalesced NHWC
    {
        const int c = t / 192, rem = t % 192, h0 = (rem / 48) * PXT, w = rem % 48;
#pragma unroll
        for (int j = 0; j < PXT; ++j)
            bufI[c * PLANE + (h0 + j) * PST + w] = first[j] - second[j];
    }
    __syncthreads();
    float* outp = out + n * NPIX;
#pragma unroll
    for (int k = 0; k < PXT; ++k) {
        int j = k * TPB + t;
        int c = j % 3, hw = j / 3, w = hw % WW, h = hw / WW;
        outp[j] = bufI[c * PLANE + h * PST + w];
    }
}

extern "C" void kernel_launch(void* const* d_in, const int* in_sizes, int n_in,
                              void* d_out, int out_size, void* d_ws, size_t ws_size,
                              hipStream_t stream) {
    const float* in = (const float*)d_in[0];
    const float* gm = (const float*)d_in[1];
    const float* gw = (const float*)d_in[2];
    const float* gg = (const float*)d_in[3];
    float* out = (float*)d_out;
    (void)d_ws; (void)ws_size;

    inrf_fused<<<NB, TPB, 0, stream>>>(in, gm, gw, gg, out);
}

// Round 2
// 83.061 us; speedup vs baseline: 3.6330x; 3.6330x over previous
//
#include <hip/hip_runtime.h>

#define KS   21
#define HH   48
#define WW   48
#define CC   3
#define NB   4
#define NPIX (HH*WW*CC)     /* 6912 */
#define NTOT (NB*NPIX)      /* 27648 */
#define TPB  576            /* 9 waves; 3c x 48 x 4 groups */
#define PXT  12             /* pixels per thread per conv pass */
#define SPAN (PXT + KS - 1) /* 32: 12 outputs + 20 halo */
#define PST  49             /* padded plane row stride (banks: 49 mod 32 = 17, odd) */
#define PLANE (HH*PST)      /* 2352 */
#define CTAN 2.8853900817779268f   /* 2*log2(e) */
/* x in [0,1): tanh(x-b) == -1 (+/-6.7e-4) for all x if b >= 5; == +1 if b <= -4 */
#define B_HI 5.0f
#define B_LO -4.0f
/* interpolation grid for S(x) = sum_q 1/(exp2(CTAN*x - cb_q)+1):
   128 intervals over [0,1], nodes at i/128 for i in -1..129 (131 nodes) so
   Catmull-Rom always has a full 4-point stencil. */
#define NNODE 131
#define INVH  128.0f

__device__ __forceinline__ float fast_exp2(float x) {
#if __has_builtin(__builtin_amdgcn_exp2f)
    return __builtin_amdgcn_exp2f(x);
#else
    return __expf(x * 0.6931471805599453f);
#endif
}
__device__ __forceinline__ float fast_rcp(float x) {
#if __has_builtin(__builtin_amdgcn_rcpf)
    return __builtin_amdgcn_rcpf(x);
#else
    return 1.0f / x;
#endif
}

// 1D L2-normalized Gaussian tap (f,i). Outer product == reference's 2D
// L2-normalized kernel (amp cancels; 2D sum-sq factorizes into (1D sum-sq)^2).
__device__ __forceinline__ float tap1d(const float* g, int f, int i) {
    float sigma  = 1.0f / g[f];
    float inv2s2 = 0.5f / (sigma * sigma);
    const float step = 21.0f / 640.0f, mean = 21.0f / 64.0f;
    float r = (float)i * step - mean;
    float v = expf(-r * r * inv2s2);
    float ss = 0.0f;
    for (int j = 0; j < KS; ++j) {
        float rj = (float)j * step - mean;
        float vj = expf(-rj * rj * inv2s2);
        ss += vj * vj;
    }
    return v * rsqrtf(ss);
}

// Horizontal conv pass, planar LDS -> planar LDS, zero padding via zeroed
// OOB window slots. Thread t: c = t/192, h = (t%192)/4, w0 = (t%4)*12.
__device__ __forceinline__ void hconv(const float* src, float* dst,
                                      const float* taps, int t) {
    const int c = t / 192, rem = t % 192, h = rem >> 2, w0 = (rem & 3) * PXT;
    const float* row = src + c * PLANE + h * PST;
    float v[SPAN];
#pragma unroll
    for (int s = 0; s < SPAN; ++s) {
        int w = w0 - 10 + s;
        v[s] = ((unsigned)w < (unsigned)WW) ? row[w] : 0.0f;
    }
    float tp[KS];
#pragma unroll
    for (int k = 0; k < KS; ++k) tp[k] = taps[c * 21 + k];
    float* drow = dst + c * PLANE + h * PST + w0;
#pragma unroll
    for (int j = 0; j < PXT; ++j) {
        float a = 0.0f;
#pragma unroll
        for (int k = 0; k < KS; ++k) a = fmaf(v[j + k], tp[k], a);
        drow[j] = a;
    }
}

// Vertical conv pass, planar LDS -> 12 registers.
// Thread t: c = t/192, hq = (t%192)/48, w = t%48; lanes 0..47 -> consecutive w.
__device__ __forceinline__ void vconv(const float* src, const float* taps,
                                      int t, float* acc) {
    const int c = t / 192, rem = t % 192, h0 = (rem / 48) * PXT, w = rem % 48;
    const float* col = src + c * PLANE + w;
    float v[SPAN];
#pragma unroll
    for (int s = 0; s < SPAN; ++s) {
        int h = h0 - 10 + s;
        v[s] = ((unsigned)h < (unsigned)HH) ? col[h * PST] : 0.0f;
    }
    float tp[KS];
#pragma unroll
    for (int k = 0; k < KS; ++k) tp[k] = taps[c * 21 + k];
#pragma unroll
    for (int j = 0; j < PXT; ++j) {
        float a = 0.0f;
#pragma unroll
        for (int k = 0; k < KS; ++k) a = fmaf(v[j + k], tp[k], a);
        acc[j] = a;
    }
}

// Single fused kernel: one block per image. All intermediates in LDS/registers.
// Phases: load(planar) -> M convs (first in regs) -> G convs -> classify/compact
// -> S(x) at 131 nodes (O(nodes*len), all threads) -> per-pixel Catmull-Rom
// interp -> W convs -> out = first - second.
__global__ __launch_bounds__(TPB) void inrf_fused(
    const float* __restrict__ in, const float* __restrict__ gm,
    const float* __restrict__ gw, const float* __restrict__ gg,
    float* __restrict__ out)
{
    __shared__ float bufI[CC * PLANE];   // input planar; later: difference
    __shared__ float bufB[CC * PLANE];   // hconv scratch; transiently: active list
    __shared__ float sm[63], sg[63], sw[63];
    __shared__ float sS[NNODE];
    __shared__ int s_len, s_net;

    const int t = threadIdx.x;
    const int n = blockIdx.x;
    const int lane = t & 63;

    // taps: 189 threads compute one 1D tap each
    if (t < 189) {
        int set = t / 63, f = (t % 63) / 21, i = t % 21;
        const float* g = (set == 0) ? gm : (set == 1) ? gg : gw;
        float v = tap1d(g, f, i);
        ((set == 0) ? sm : (set == 1) ? sg : sw)[t % 63] = v;
    }
    if (t < NNODE) sS[t] = 0.0f;
    if (t == 0) { s_len = 0; s_net = 0; }

    // load NHWC -> planar [c][h][w] (row stride 49)
    const float* imgp = in + n * NPIX;
#pragma unroll
    for (int k = 0; k < PXT; ++k) {
        int j = k * TPB + t;
        int c = j % 3, hw = j / 3, w = hw % WW, h = hw / WW;
        bufI[c * PLANE + h * PST + w] = imgp[j];
    }
    __syncthreads();

    // M path: first term (stays in registers until the end)
    hconv(bufI, bufB, sm, t);
    __syncthreads();
    float first[PXT];
    vconv(bufB, sm, t, first);
    __syncthreads();

    // G path: blurred
    hconv(bufI, bufB, sg, t);
    __syncthreads();
    float bb[PXT];
    vconv(bufB, sg, t, bb);
    __syncthreads();                     // all reads of bufB done -> reuse for actives

    // classify + compact (active list into bufB; net count via ballots)
    int wnet = 0;
#pragma unroll
    for (int j = 0; j < PXT; ++j) {
        bool sp = (bb[j] <= B_LO);       // tanh == +1 for all x
        bool sn = (bb[j] >= B_HI);       // tanh == -1 for all x
        unsigned long long bp = __ballot(sp), bn = __ballot(sn);
        if (lane == 0) wnet += __popcll(bp) - __popcll(bn);
        if (!(sp | sn)) {
            int pos = atomicAdd(&s_len, 1);
            bufB[pos] = CTAN * bb[j];
        }
    }
    if (lane == 0) atomicAdd(&s_net, wnet);
    __syncthreads();

    const int len = s_len;
    const float netf = (float)s_net;

    // node phase: S at node a (x = (a-1)/128), a = t % 131; q striped over the
    // 4 (or 5, for a < 52) threads sharing this node. O(131*len) total.
    if (len > 0) {
        const int node = t % NNODE, stripe = t / NNODE;
        const int nst = (node < (TPB - 4 * NNODE)) ? 5 : 4;   /* 576-524=52 */
        const float cn = CTAN * ((float)(node - 1) * (1.0f / INVH));
        float pacc = 0.0f;
        for (int q = stripe; q < len; q += nst)
            pacc += fast_rcp(fast_exp2(cn - bufB[q]) + 1.0f);
        atomicAdd(&sS[node], pacc);
    }
    __syncthreads();

    // per-pixel: d = (net + len - 2*S(x)) / NPIX via Catmull-Rom on sS.
    // x read and d written in place (each pixel owned by exactly one thread)
    {
        const int c = t / 192, rem = t % 192, h0 = (rem / 48) * PXT, w = rem % 48;
        float* col = bufI + c * PLANE + w;
#pragma unroll
        for (int j = 0; j < PXT; ++j) {
            float x = col[(h0 + j) * PST];
            float u = x * INVH;
            int i0 = (int)floorf(u);
            i0 = min(max(i0, 0), 127);
            float s = u - (float)i0;
            float p0 = sS[i0], p1 = sS[i0 + 1], p2 = sS[i0 + 2], p3 = sS[i0 + 3];
            float Sx = p1 + 0.5f * s * ((p2 - p0)
                     + s * ((2.0f * p0 - 5.0f * p1 + 4.0f * p2 - p3)
                     + s * (3.0f * (p1 - p2) + p3 - p0)));
            col[(h0 + j) * PST] = (netf + (float)len - 2.0f * Sx) * (1.0f / (float)NPIX);
        }
    }
    __syncthreads();                     // d complete; active list dead

    // W path on difference
    hconv(bufI, bufB, sw, t);
    __syncthreads();
    float second[PXT];
    vconv(bufB, sw, t, second);
    __syncthreads();                     // all reads of bufI done; safe to reuse

    // out = first - second, staged planar then stored coalesced NHWC
    {
        const int c = t / 192, rem = t % 192, h0 = (rem / 48) * PXT, w = rem % 48;
#pragma unroll
        for (int j = 0; j < PXT; ++j)
            bufI[c * PLANE + (h0 + j) * PST + w] = first[j] - second[j];
    }
    __syncthreads();
    float* outp = out + n * NPIX;
#pragma unroll
    for (int k = 0; k < PXT; ++k) {
        int j = k * TPB + t;
        int c = j % 3, hw = j / 3, w = hw % WW, h = hw / WW;
        outp[j] = bufI[c * PLANE + h * PST + w];
    }
}

extern "C" void kernel_launch(void* const* d_in, const int* in_sizes, int n_in,
                              void* d_out, int out_size, void* d_ws, size_t ws_size,
                              hipStream_t stream) {
    const float* in = (const float*)d_in[0];
    const float* gm = (const float*)d_in[1];
    const float* gw = (const float*)d_in[2];
    const float* gg = (const float*)d_in[3];
    float* out = (float*)d_out;
    (void)d_ws; (void)ws_size;

    inrf_fused<<<NB, TPB, 0, stream>>>(in, gm, gw, gg, out);
}

// Round 3
// 82.049 us; speedup vs baseline: 3.6778x; 1.0123x over previous
//
#include <hip/hip_runtime.h>

#define KS   21
#define HH   48
#define WW   48
#define CC   3
#define ROW  (WW*CC)      /* 144 */
#define NB   4
#define NPIX (HH*WW*CC)   /* 6912 */
#define NTOT (NB*NPIX)    /* 27648 */
#define TPB  256
#define NBLK (NTOT/TPB)   /* 108 */
#define SEGS (NPIX/TPB)   /* 27 segments per image */
#define CTAN 2.8853900817779268f   /* 2*log2(e) */
/* x in [0,1): tanh(x-b) == -1 (+/-6.7e-4) for all x if b >= 5; == +1 if b <= -4 */
#define B_HI 5.0f
#define B_LO -4.0f
/* interpolation grid for S(x) = sum_q 1/(exp2(CTAN*x - cb_q)+1):
   128 intervals over [0,1], nodes at (i-1)/128 for i in 0..130 so Catmull-Rom
   always has a full 4-point stencil for x in [0,1]. */
#define NNODE 131
#define INVH  128.0f

__device__ __forceinline__ float fast_exp2(float x) {
#if __has_builtin(__builtin_amdgcn_exp2f)
    return __builtin_amdgcn_exp2f(x);
#else
    return __expf(x * 0.6931471805599453f);
#endif
}
__device__ __forceinline__ float fast_rcp(float x) {
#if __has_builtin(__builtin_amdgcn_rcpf)
    return __builtin_amdgcn_rcpf(x);
#else
    return 1.0f / x;
#endif
}

// 1D L2-normalized Gaussian tap (f,i). Outer product == reference's 2D
// L2-normalized kernel (amp cancels; 2D sum-sq factorizes into (1D sum-sq)^2).
__device__ __forceinline__ float tap1d(const float* g, int f, int i) {
    float sigma  = 1.0f / g[f];
    float inv2s2 = 0.5f / (sigma * sigma);
    const float step = 21.0f / 640.0f, mean = 21.0f / 64.0f;
    float r = (float)i * step - mean;
    float v = expf(-r * r * inv2s2);
    float ss = 0.0f;
    for (int j = 0; j < KS; ++j) {
        float rj = (float)j * step - mean;
        float vj = expf(-rj * rj * inv2s2);
        ss += vj * vj;
    }
    return v * rsqrtf(ss);
}

// A: horizontal conv with m and g taps (shared input loads). Fully unrolled:
// clamped addresses + zero-masked taps instead of variable loop bounds.
__global__ __launch_bounds__(TPB) void hconv_mg(
    const float* __restrict__ in, const float* __restrict__ gm,
    const float* __restrict__ gg, float* __restrict__ hm, float* __restrict__ hg)
{
    __shared__ float sm[63], sg[63];
    const int t = threadIdx.x;
    if (t < 126) {
        int set = t / 63, f = (t % 63) / 21, i = t % 21;
        float v = tap1d(set ? gg : gm, f, i);
        (set ? sg : sm)[t % 63] = v;
    }
    __syncthreads();
    const int idx = blockIdx.x * TPB + t;
    const int c = idx % CC, w = (idx / CC) % WW;
    const int rowstart = idx - w * CC;          // (n,h,0,c)
    float tm[KS], tg[KS];
#pragma unroll
    for (int k = 0; k < KS; ++k) { tm[k] = sm[c * 21 + k]; tg[k] = sg[c * 21 + k]; }
    float am = 0.f, ag = 0.f;
#pragma unroll
    for (int k = 0; k < KS; ++k) {
        int wc = w + k - 10;
        int wcc = min(max(wc, 0), WW - 1);
        float v = in[rowstart + wcc * CC];
        bool ok = (unsigned)wc < (unsigned)WW;
        am = fmaf(v, ok ? tm[k] : 0.f, am);
        ag = fmaf(v, ok ? tg[k] : 0.f, ag);
    }
    hm[idx] = am;
    hg[idx] = ag;
}

// B: vertical conv (m -> first, g -> blur) + classify + per-block-segment
// compaction (no global atomics; segcnt/netcnt owned by this block).
__global__ __launch_bounds__(TPB) void vconv_mg(
    const float* __restrict__ hm, const float* __restrict__ hg,
    const float* __restrict__ gm, const float* __restrict__ gg,
    float* __restrict__ first, float* __restrict__ active,
    int* __restrict__ segcnt, int* __restrict__ netcnt)
{
    __shared__ float sm[63], sg[63];
    __shared__ int wcnt[4], wnet[4];
    const int t = threadIdx.x;
    if (t < 126) {
        int set = t / 63, f = (t % 63) / 21, i = t % 21;
        float v = tap1d(set ? gg : gm, f, i);
        (set ? sg : sm)[t % 63] = v;
    }
    __syncthreads();
    const int idx = blockIdx.x * TPB + t;
    const int c = idx % CC, h = (idx / ROW) % HH;
    const int n = blockIdx.x / SEGS, seg = blockIdx.x % SEGS;
    float tm[KS], tg[KS];
#pragma unroll
    for (int k = 0; k < KS; ++k) { tm[k] = sm[c * 21 + k]; tg[k] = sg[c * 21 + k]; }
    float am = 0.f, ag = 0.f;
#pragma unroll
    for (int k = 0; k < KS; ++k) {
        int hc = h + k - 10;
        int hcc = min(max(hc, 0), HH - 1);
        int off = idx + (hcc - h) * ROW;
        bool ok = (unsigned)hc < (unsigned)HH;
        am = fmaf(hm[off], ok ? tm[k] : 0.f, am);
        ag = fmaf(hg[off], ok ? tg[k] : 0.f, ag);
    }
    first[idx] = am;

    const float b = ag;
    const bool satpos = (b <= B_LO);             // tanh == +1 for all x
    const bool satneg = (b >= B_HI);             // tanh == -1 for all x
    const bool act = !(satpos || satneg);
    const int lane = t & 63, wid = t >> 6;
    unsigned long long mb = __ballot(act);
    int cnt = __popcll(mb);
    int netc = __popcll(__ballot(satpos)) - __popcll(__ballot(satneg));
    if (lane == 0) { wcnt[wid] = cnt; wnet[wid] = netc; }
    __syncthreads();
    int pre = 0;
    for (int j = 0; j < wid; ++j) pre += wcnt[j];
    if (act) {
        int pos = pre + __popcll(mb & ((1ull << lane) - 1ull));
        active[n * NPIX + seg * TPB + pos] = CTAN * b;
    }
    if (t == 0) {
        segcnt[blockIdx.x] = wcnt[0] + wcnt[1] + wcnt[2] + wcnt[3];
        netcnt[blockIdx.x] = wnet[0] + wnet[1] + wnet[2] + wnet[3];
    }
}

// C: node table. Block (node, n): S_n(x_node) = sum over image n's active list
// of sigmoid(cn - cb). O(NNODE * len) total, one wave per block.
__global__ __launch_bounds__(64) void node_kernel(
    const float* __restrict__ active, const int* __restrict__ segcnt,
    float* __restrict__ sS)
{
    const int node = blockIdx.x, n = blockIdx.y;
    const int t = threadIdx.x;
    const float cn = CTAN * ((float)(node - 1) * (1.0f / INVH));
    float acc = 0.0f;
    for (int s = 0; s < SEGS; ++s) {
        int cnt = segcnt[n * SEGS + s];
        const float* ap = active + n * NPIX + s * TPB;
        for (int q = t; q < cnt; q += 64)
            acc += fast_rcp(fast_exp2(cn - ap[q]) + 1.0f);
    }
#pragma unroll
    for (int off = 32; off > 0; off >>= 1) acc += __shfl_down(acc, off, 64);
    if (t == 0) sS[n * NNODE + node] = acc;
}

// D: horizontal conv with w taps of d(x) = (net + len - 2*S(x))/NPIX, with
// S(x) Catmull-Rom-interpolated from the per-image node table (LDS-staged).
__global__ __launch_bounds__(TPB) void hconv_w_interp(
    const float* __restrict__ in, const float* __restrict__ gw,
    const int* __restrict__ segcnt, const int* __restrict__ netcnt,
    const float* __restrict__ sS, float* __restrict__ tmp)
{
    __shared__ float sw[63];
    __shared__ float ss[NNODE];
    const int t = threadIdx.x;
    if (t < 63) sw[t] = tap1d(gw, t / 21, t % 21);
    const int n = blockIdx.x / SEGS;             // n uniform per block
    if (t < NNODE) ss[t] = sS[n * NNODE + t];
    float nl = 0.f;
    for (int s = 0; s < SEGS; ++s)
        nl += (float)(netcnt[n * SEGS + s] + segcnt[n * SEGS + s]);
    __syncthreads();
    const int idx = blockIdx.x * TPB + t;
    const int c = idx % CC, w = (idx / CC) % WW;
    const int rowstart = idx - w * CC;
    float tw[KS];
#pragma unroll
    for (int k = 0; k < KS; ++k) tw[k] = sw[c * 21 + k];
    float a = 0.f;
#pragma unroll
    for (int k = 0; k < KS; ++k) {
        int wc = w + k - 10;
        int wcc = min(max(wc, 0), WW - 1);
        float x = in[rowstart + wcc * CC];
        float u = x * INVH;
        int i0 = (int)floorf(u);
        i0 = min(max(i0, 0), 127);
        float s = u - (float)i0;
        float p0 = ss[i0], p1 = ss[i0 + 1], p2 = ss[i0 + 2], p3 = ss[i0 + 3];
        float Sx = p1 + 0.5f * s * ((p2 - p0)
                 + s * ((2.0f * p0 - 5.0f * p1 + 4.0f * p2 - p3)
                 + s * (3.0f * (p1 - p2) + p3 - p0)));
        float d = (nl - 2.0f * Sx) * (1.0f / (float)NPIX);
        bool ok = (unsigned)wc < (unsigned)WW;
        a = fmaf(d, ok ? tw[k] : 0.f, a);
    }
    tmp[idx] = a;
}

// E: vertical conv with w taps; out = first - second.
__global__ __launch_bounds__(TPB) void vconv_w_sub(
    const float* __restrict__ tmp, const float* __restrict__ gw,
    const float* __restrict__ first, float* __restrict__ out)
{
    __shared__ float sw[63];
    const int t = threadIdx.x;
    if (t < 63) sw[t] = tap1d(gw, t / 21, t % 21);
    __syncthreads();
    const int idx = blockIdx.x * TPB + t;
    const int c = idx % CC, h = (idx / ROW) % HH;
    float tw[KS];
#pragma unroll
    for (int k = 0; k < KS; ++k) tw[k] = sw[c * 21 + k];
    float a = 0.f;
#pragma unroll
    for (int k = 0; k < KS; ++k) {
        int hc = h + k - 10;
        int hcc = min(max(hc, 0), HH - 1);
        bool ok = (unsigned)hc < (unsigned)HH;
        a = fmaf(tmp[idx + (hcc - h) * ROW], ok ? tw[k] : 0.f, a);
    }
    out[idx] = first[idx] - a;
}

extern "C" void kernel_launch(void* const* d_in, const int* in_sizes, int n_in,
                              void* d_out, int out_size, void* d_ws, size_t ws_size,
                              hipStream_t stream) {
    const float* in = (const float*)d_in[0];
    const float* gm = (const float*)d_in[1];
    const float* gw = (const float*)d_in[2];
    const float* gg = (const float*)d_in[3];
    float* out = (float*)d_out;

    float* wsf    = (float*)d_ws;
    float* hm     = wsf;                    // NTOT
    float* hg     = hm + NTOT;              // NTOT
    float* first  = hg + NTOT;              // NTOT
    float* active = first + NTOT;           // NTOT (worst case)
    float* tmpb   = active + NTOT;          // NTOT
    float* sS     = tmpb + NTOT;            // NB*NNODE
    int*   segcnt = (int*)(sS + NB * NNODE);// NBLK
    int*   netcnt = segcnt + NBLK;          // NBLK

    hconv_mg<<<NBLK, TPB, 0, stream>>>(in, gm, gg, hm, hg);
    vconv_mg<<<NBLK, TPB, 0, stream>>>(hm, hg, gm, gg, first, active, segcnt, netcnt);
    node_kernel<<<dim3(NNODE, NB), 64, 0, stream>>>(active, segcnt, sS);
    hconv_w_interp<<<NBLK, TPB, 0, stream>>>(in, gw, segcnt, netcnt, sS, tmpb);
    vconv_w_sub<<<NBLK, TPB, 0, stream>>>(tmpb, gw, first, out);
}

// Round 4
// 76.151 us; speedup vs baseline: 3.9626x; 1.0775x over previous
//
#include <hip/hip_runtime.h>

#define KS   21
#define HH   48
#define WW   48
#define CC   3
#define ROW  (WW*CC)      /* 144 */
#define NB   4
#define NPIX (HH*WW*CC)   /* 6912 */
#define NTOT (NB*NPIX)    /* 27648 */
#define TPB  256
#define NBLK (NTOT/TPB)   /* 108 */
#define CTAN 2.8853900817779268f   /* 2*log2(e) */
/* interpolation grid for T(x) = sum_p tanh(x - b_p):
   128 intervals over [0,1], nodes at (i-1)/128 for i in 0..130 so Catmull-Rom
   always has a full 4-point stencil for x in [0,1]. */
#define NNODE 131
#define INVH  128.0f

__device__ __forceinline__ float fast_exp2(float x) {
#if __has_builtin(__builtin_amdgcn_exp2f)
    return __builtin_amdgcn_exp2f(x);
#else
    return __expf(x * 0.6931471805599453f);
#endif
}
__device__ __forceinline__ float fast_rcp(float x) {
#if __has_builtin(__builtin_amdgcn_rcpf)
    return __builtin_amdgcn_rcpf(x);
#else
    return 1.0f / x;
#endif
}

// 1D L2-normalized Gaussian tap (f,i). Outer product == reference's 2D
// L2-normalized kernel (amp cancels; 2D sum-sq factorizes into (1D sum-sq)^2).
__device__ __forceinline__ float tap1d(const float* g, int f, int i) {
    float sigma  = 1.0f / g[f];
    float inv2s2 = 0.5f / (sigma * sigma);
    const float step = 21.0f / 640.0f, mean = 21.0f / 64.0f;
    float r = (float)i * step - mean;
    float v = expf(-r * r * inv2s2);
    float ss = 0.0f;
    for (int j = 0; j < KS; ++j) {
        float rj = (float)j * step - mean;
        float vj = expf(-rj * rj * inv2s2);
        ss += vj * vj;
    }
    return v * rsqrtf(ss);
}

// A: horizontal conv with m and g taps (shared input loads). Fully unrolled:
// clamped addresses + zero-masked taps instead of variable loop bounds.
__global__ __launch_bounds__(TPB) void hconv_mg(
    const float* __restrict__ in, const float* __restrict__ gm,
    const float* __restrict__ gg, float* __restrict__ hm, float* __restrict__ hg)
{
    __shared__ float sm[63], sg[63];
    const int t = threadIdx.x;
    if (t < 126) {
        int set = t / 63, f = (t % 63) / 21, i = t % 21;
        float v = tap1d(set ? gg : gm, f, i);
        (set ? sg : sm)[t % 63] = v;
    }
    __syncthreads();
    const int idx = blockIdx.x * TPB + t;
    const int c = idx % CC, w = (idx / CC) % WW;
    const int rowstart = idx - w * CC;          // (n,h,0,c)
    float tm[KS], tg[KS];
#pragma unroll
    for (int k = 0; k < KS; ++k) { tm[k] = sm[c * 21 + k]; tg[k] = sg[c * 21 + k]; }
    float am = 0.f, ag = 0.f;
#pragma unroll
    for (int k = 0; k < KS; ++k) {
        int wc = w + k - 10;
        int wcc = min(max(wc, 0), WW - 1);
        float v = in[rowstart + wcc * CC];
        bool ok = (unsigned)wc < (unsigned)WW;
        am = fmaf(v, ok ? tm[k] : 0.f, am);
        ag = fmaf(v, ok ? tg[k] : 0.f, ag);
    }
    hm[idx] = am;
    hg[idx] = ag;
}

// B: vertical conv (m -> first, g -> dense scaled blur). No compaction, no
// counters, no atomics — the node scan consumes the dense blur directly.
__global__ __launch_bounds__(TPB) void vconv_mg(
    const float* __restrict__ hm, const float* __restrict__ hg,
    const float* __restrict__ gm, const float* __restrict__ gg,
    float* __restrict__ first, float* __restrict__ cb)
{
    __shared__ float sm[63], sg[63];
    const int t = threadIdx.x;
    if (t < 126) {
        int set = t / 63, f = (t % 63) / 21, i = t % 21;
        float v = tap1d(set ? gg : gm, f, i);
        (set ? sg : sm)[t % 63] = v;
    }
    __syncthreads();
    const int idx = blockIdx.x * TPB + t;
    const int c = idx % CC, h = (idx / ROW) % HH;
    float tm[KS], tg[KS];
#pragma unroll
    for (int k = 0; k < KS; ++k) { tm[k] = sm[c * 21 + k]; tg[k] = sg[c * 21 + k]; }
    float am = 0.f, ag = 0.f;
#pragma unroll
    for (int k = 0; k < KS; ++k) {
        int hc = h + k - 10;
        int hcc = min(max(hc, 0), HH - 1);
        int off = idx + (hcc - h) * ROW;
        bool ok = (unsigned)hc < (unsigned)HH;
        am = fmaf(hm[off], ok ? tm[k] : 0.f, am);
        ag = fmaf(hg[off], ok ? tg[k] : 0.f, ag);
    }
    first[idx] = am;
    cb[idx] = CTAN * ag;                 // 2*log2(e)*blur, ready for exp2
}

// C: node table. Block (node, n): T_n(x_node) = sum over ALL pixels of
// tanh(x_node - b_p) = NPIX - 2*sum sigma. Dense branch-free coalesced scan —
// exp2/rcp saturate correctly (exp2->0/inf, rcp->1/0), so no classification,
// no dependent-load chains. 27 iters/thread, 524 blocks.
__global__ __launch_bounds__(TPB) void node_kernel(
    const float* __restrict__ cb, float* __restrict__ sT)
{
    __shared__ float red[TPB / 64];
    const int node = blockIdx.x, n = blockIdx.y;
    const int t = threadIdx.x;
    const float cn = CTAN * ((float)(node - 1) * (1.0f / INVH));
    const float* p = cb + n * NPIX;
    float acc = 0.0f;
#pragma unroll
    for (int i = 0; i < NPIX / TPB; ++i)
        acc += fast_rcp(fast_exp2(cn - p[i * TPB + t]) + 1.0f);
#pragma unroll
    for (int off = 32; off > 0; off >>= 1) acc += __shfl_down(acc, off, 64);
    if ((t & 63) == 0) red[t >> 6] = acc;
    __syncthreads();
    if (t == 0)
        sT[n * NNODE + node] =
            (float)NPIX - 2.0f * (red[0] + red[1] + red[2] + red[3]);
}

// D: horizontal conv with w taps of d(x) = T(x)/NPIX, T Catmull-Rom-
// interpolated from the per-image node table (LDS-staged, 131 floats only).
__global__ __launch_bounds__(TPB) void hconv_w_interp(
    const float* __restrict__ in, const float* __restrict__ gw,
    const float* __restrict__ sT, float* __restrict__ tmp)
{
    __shared__ float sw[63];
    __shared__ float ss[NNODE];
    const int t = threadIdx.x;
    if (t < 63) sw[t] = tap1d(gw, t / 21, t % 21);
    const int n = blockIdx.x / (NPIX / TPB);     // n uniform per block
    if (t < NNODE) ss[t] = sT[n * NNODE + t];
    __syncthreads();
    const int idx = blockIdx.x * TPB + t;
    const int c = idx % CC, w = (idx / CC) % WW;
    const int rowstart = idx - w * CC;
    float tw[KS];
#pragma unroll
    for (int k = 0; k < KS; ++k) tw[k] = sw[c * 21 + k];
    float a = 0.f;
#pragma unroll
    for (int k = 0; k < KS; ++k) {
        int wc = w + k - 10;
        int wcc = min(max(wc, 0), WW - 1);
        float x = in[rowstart + wcc * CC];
        float u = x * INVH;
        int i0 = (int)floorf(u);
        i0 = min(max(i0, 0), 127);
        float s = u - (float)i0;
        float p0 = ss[i0], p1 = ss[i0 + 1], p2 = ss[i0 + 2], p3 = ss[i0 + 3];
        float Tx = p1 + 0.5f * s * ((p2 - p0)
                 + s * ((2.0f * p0 - 5.0f * p1 + 4.0f * p2 - p3)
                 + s * (3.0f * (p1 - p2) + p3 - p0)));
        bool ok = (unsigned)wc < (unsigned)WW;
        a = fmaf(Tx * (1.0f / (float)NPIX), ok ? tw[k] : 0.f, a);
    }
    tmp[idx] = a;
}

// E: vertical conv with w taps; out = first - second.
__global__ __launch_bounds__(TPB) void vconv_w_sub(
    const float* __restrict__ tmp, const float* __restrict__ gw,
    const float* __restrict__ first, float* __restrict__ out)
{
    __shared__ float sw[63];
    const int t = threadIdx.x;
    if (t < 63) sw[t] = tap1d(gw, t / 21, t % 21);
    __syncthreads();
    const int idx = blockIdx.x * TPB + t;
    const int c = idx % CC, h = (idx / ROW) % HH;
    float tw[KS];
#pragma unroll
    for (int k = 0; k < KS; ++k) tw[k] = sw[c * 21 + k];
    float a = 0.f;
#pragma unroll
    for (int k = 0; k < KS; ++k) {
        int hc = h + k - 10;
        int hcc = min(max(hc, 0), HH - 1);
        bool ok = (unsigned)hc < (unsigned)HH;
        a = fmaf(tmp[idx + (hcc - h) * ROW], ok ? tw[k] : 0.f, a);
    }
    out[idx] = first[idx] - a;
}

extern "C" void kernel_launch(void* const* d_in, const int* in_sizes, int n_in,
                              void* d_out, int out_size, void* d_ws, size_t ws_size,
                              hipStream_t stream) {
    const float* in = (const float*)d_in[0];
    const float* gm = (const float*)d_in[1];
    const float* gw = (const float*)d_in[2];
    const float* gg = (const float*)d_in[3];
    float* out = (float*)d_out;

    float* wsf   = (float*)d_ws;
    float* hm    = wsf;                  // NTOT
    float* hg    = hm + NTOT;            // NTOT
    float* first = hg + NTOT;            // NTOT
    float* cb    = first + NTOT;         // NTOT (dense scaled blur)
    float* tmpb  = cb + NTOT;            // NTOT
    float* sT    = tmpb + NTOT;          // NB*NNODE

    hconv_mg<<<NBLK, TPB, 0, stream>>>(in, gm, gg, hm, hg);
    vconv_mg<<<NBLK, TPB, 0, stream>>>(hm, hg, gm, gg, first, cb);
    node_kernel<<<dim3(NNODE, NB), TPB, 0, stream>>>(cb, sT);
    hconv_w_interp<<<NBLK, TPB, 0, stream>>>(in, gw, sT, tmpb);
    vconv_w_sub<<<NBLK, TPB, 0, stream>>>(tmpb, gw, first, out);
}